// Round 3
// baseline (598.338 us; speedup 1.0000x reference)
//
#include <hip/hip_runtime.h>
#include <hip/hip_bf16.h>

#define DEVINL __device__ __forceinline__

constexpr int N = 50000;
constexpr int E = 800000;
constexpr int F_IN = 128;
constexpr int H = 96;
constexpr int C = 16;
constexpr int G = 128;
constexpr int S = 8;   // pooling chunks per graph

// fp32 weight table layout in ws
constexpr int OFF_W0  = 0;                    // [128][96]
constexpr int OFF_W1  = OFF_W0 + F_IN * H;    // [96][96]
constexpr int OFF_W2  = OFF_W1 + H * H;
constexpr int OFF_WC1 = OFF_W2 + H * H;       // [192][96]
constexpr int OFF_WC2 = OFF_WC1 + 2 * H * H;  // [96][16]
constexpr int OFF_B0  = OFF_WC2 + H * C;
constexpr int OFF_B1  = OFF_B0 + H;
constexpr int OFF_B2  = OFF_B1 + H;
constexpr int OFF_BC1 = OFF_B2 + H;
constexpr int OFF_BC2 = OFF_BC1 + H;
constexpr int WF_TOT  = OFF_BC2 + C;          // 51088 floats

DEVINL float gelu_f(float x) {
    return 0.5f * x * (1.0f + erff(x * 0.70710678118654752440f));
}

// ---------------- dtype detection ----------------
// flags[0]: edge_index stored as int64 (1) or int32 (0)
// flags[1]: batch stored as int64 (1) or int32 (0)
// flags[2]: float tensors stored as fp32 (1) or bf16 (0)
__global__ void k_detect(const int* __restrict__ eidx, const int* __restrict__ batch,
                         const unsigned short* __restrict__ xu, int* __restrict__ flags) {
    if (threadIdx.x == 0 && blockIdx.x == 0) {
        int z = 0;
        for (int i = 1; i < 16; i += 2) z |= eidx[i];         // src ids: random, ~never all 0
        flags[0] = (z == 0) ? 1 : 0;
        z = 0;
        for (int i = 20001; i < 20032; i += 2) z |= batch[i]; // sorted batch ~51 here if int32
        flags[1] = (z == 0) ? 1 : 0;
        int bad = 0;
        for (int i = 0; i < 128; i += 2) {                    // even bf16 slots of x
            int ex = (xu[i] >> 7) & 0xFF;
            if (ex >= 132) bad = 1;                           // |v|>=64: impossible for bf16 N(0,1)
        }
        flags[2] = bad;                                       // garbage exponents => fp32 storage
    }
}

DEVINL int ld_src(const int* e, int i64, int i) { return i64 ? e[2 * i] : e[i]; }
DEVINL int ld_dst(const int* e, int i64, int i) { return i64 ? e[2 * (E + i)] : e[E + i]; }
DEVINL int ld_idx(const int* a, int i64, int i) { return i64 ? a[2 * i] : a[i]; }

// ---------------- weight conversion to fp32 table ----------------
__global__ void k_convert(const void* W0, const void* W1, const void* W2,
                          const void* Wc1, const void* Wc2,
                          const void* b0, const void* b1, const void* b2,
                          const void* bc1, const void* bc2,
                          const int* __restrict__ flags, float* __restrict__ wf) {
    int i = blockIdx.x * 256 + threadIdx.x;
    if (i >= WF_TOT) return;
    int f32 = flags[2];
    const void* src; int j;
    if      (i < OFF_W1)  { src = W0;  j = i - OFF_W0; }
    else if (i < OFF_W2)  { src = W1;  j = i - OFF_W1; }
    else if (i < OFF_WC1) { src = W2;  j = i - OFF_W2; }
    else if (i < OFF_WC2) { src = Wc1; j = i - OFF_WC1; }
    else if (i < OFF_B0)  { src = Wc2; j = i - OFF_WC2; }
    else if (i < OFF_B1)  { src = b0;  j = i - OFF_B0; }
    else if (i < OFF_B2)  { src = b1;  j = i - OFF_B1; }
    else if (i < OFF_BC1) { src = b2;  j = i - OFF_B2; }
    else if (i < OFF_BC2) { src = bc1; j = i - OFF_BC1; }
    else                  { src = bc2; j = i - OFF_BC2; }
    wf[i] = f32 ? ((const float*)src)[j]
                : __bfloat162float(((const __hip_bfloat16*)src)[j]);
}

// ---------------- degree / dis ----------------
__global__ void k_count_deg(const int* __restrict__ eidx, const int* __restrict__ flags,
                            int* __restrict__ cnt) {
    int e = blockIdx.x * 256 + threadIdx.x;
    int i64 = flags[0];
    if (e < E) atomicAdd(&cnt[ld_dst(eidx, i64, e)], 1);
}

__global__ void k_dis(const int* __restrict__ cnt, float* __restrict__ dis) {
    int n = blockIdx.x * 256 + threadIdx.x;
    if (n < N) dis[n] = rsqrtf((float)cnt[n] + 2.0f);
}

// ---------------- exclusive scan over N counts ----------------
__global__ __launch_bounds__(1024) void k_scan1(const int* __restrict__ cnt,
                                                int* __restrict__ rp, int* __restrict__ bsum) {
    __shared__ int sd[1024];
    int t = threadIdx.x;
    int i = blockIdx.x * 1024 + t;
    int v = (i < N) ? cnt[i] : 0;
    sd[t] = v; __syncthreads();
    for (int off = 1; off < 1024; off <<= 1) {
        int u = (t >= off) ? sd[t - off] : 0;
        __syncthreads();
        sd[t] += u;
        __syncthreads();
    }
    if (i < N) rp[i] = sd[t] - v;
    if (t == 1023) bsum[blockIdx.x] = sd[1023];
}

__global__ void k_scan2(int* __restrict__ bsum, int nb) {
    __shared__ int sd[64];
    int t = threadIdx.x;
    int v = (t < nb) ? bsum[t] : 0;
    sd[t] = v; __syncthreads();
    for (int off = 1; off < 64; off <<= 1) {
        int u = (t >= off) ? sd[t - off] : 0;
        __syncthreads();
        sd[t] += u;
        __syncthreads();
    }
    if (t < nb) bsum[t] = sd[t] - v;
}

__global__ __launch_bounds__(1024) void k_scan3(int* __restrict__ rp, const int* __restrict__ bsum,
                                                int* __restrict__ cur) {
    int t = threadIdx.x;
    int i = blockIdx.x * 1024 + t;
    if (i < N) { int v = rp[i] + bsum[blockIdx.x]; rp[i] = v; cur[i] = v; }
    if (i == 0) rp[N] = E;
}

// ---------------- CSR scatter (by dst), store (src, dis[src]) ----------------
__global__ void k_scatter(const int* __restrict__ eidx, const int* __restrict__ flags,
                          const float* __restrict__ dis, int* __restrict__ cur,
                          int2* __restrict__ csr) {
    int e = blockIdx.x * 256 + threadIdx.x;
    int i64 = flags[0];
    if (e < E) {
        int s = ld_src(eidx, i64, e), d = ld_dst(eidx, i64, e);
        int p = atomicAdd(&cur[d], 1);
        csr[p] = make_int2(s, __float_as_int(dis[s]));
    }
}

// ---------------- node GEMM: out[N,96] = op(in[N,K]) @ Wf[K,96] ----------------
template<int K, int KC, bool RAW_IN, bool GELU_IN>
__global__ __launch_bounds__(256) void k_gemm(const void* __restrict__ inp,
                                              const float* __restrict__ Wf,
                                              const int* __restrict__ flags,
                                              float* __restrict__ out) {
    constexpr int R = 64;
    constexpr int NC = K / KC;
    __shared__ __align__(16) float xs[KC][R + 4];
    __shared__ float wsh[KC * 96];
    const int t = threadIdx.x;
    const int r0 = blockIdx.x * R;
    const int xf32 = RAW_IN ? flags[2] : 0;

    const int ty = t >> 4;
    const int tx = t & 15;
    float acc[4][6];
#pragma unroll
    for (int i = 0; i < 4; ++i)
#pragma unroll
        for (int j = 0; j < 6; ++j) acc[i][j] = 0.f;

    for (int c = 0; c < NC; ++c) {
        if (c) __syncthreads();
        for (int idx = t; idx < KC * 96; idx += 256)
            wsh[idx] = Wf[c * KC * 96 + idx];
        for (int idx = t; idx < R * KC; idx += 256) {
            int r = idx / KC, kk = idx - r * KC;
            int row = r0 + r, k = c * KC + kk;
            float v = 0.f;
            if (row < N) {
                if (RAW_IN) {
                    if (xf32) v = ((const float*)inp)[(size_t)row * K + k];
                    else      v = __bfloat162float(((const __hip_bfloat16*)inp)[(size_t)row * K + k]);
                } else {
                    v = ((const float*)inp)[(size_t)row * K + k];
                    if (GELU_IN) v = gelu_f(v);
                }
            }
            xs[kk][r] = v;
        }
        __syncthreads();

#pragma unroll 4
        for (int kk = 0; kk < KC; ++kk) {
            float4 av = *(const float4*)&xs[kk][ty * 4];
            float a[4] = {av.x, av.y, av.z, av.w};
            float b[6];
#pragma unroll
            for (int j = 0; j < 6; ++j) b[j] = wsh[kk * 96 + tx * 6 + j];
#pragma unroll
            for (int i = 0; i < 4; ++i)
#pragma unroll
                for (int j = 0; j < 6; ++j)
                    acc[i][j] = fmaf(a[i], b[j], acc[i][j]);
        }
    }

#pragma unroll
    for (int i = 0; i < 4; ++i) {
        int row = r0 + ty * 4 + i;
        if (row < N) {
            float* o = out + (size_t)row * 96 + tx * 6;
#pragma unroll
            for (int j = 0; j < 6; ++j) o[j] = acc[i][j];
        }
    }
}

// ---------------- aggregation: out = res + dis[n]*sum + 2*dis^2*xw[n] + b ----------------
__global__ __launch_bounds__(256) void k_aggr(const float* __restrict__ xw, const float* res,
                                              const int2* __restrict__ csr, const int* __restrict__ rp,
                                              const float* __restrict__ dis,
                                              const float* __restrict__ bias, float* out) {
    int wid = threadIdx.x >> 6, lane = threadIdx.x & 63;
    int n = blockIdx.x * 4 + wid;
    if (n >= N) return;
    int e0 = rp[n], e1 = rp[n + 1];
    bool act = lane < 48;
    int c = lane * 2;
    float a0 = 0.f, a1 = 0.f;
    for (int e = e0; e < e1; ++e) {
        int2 pk = csr[e];
        float wv = __int_as_float(pk.y);
        if (act) {
            float2 v = *(const float2*)(xw + (size_t)pk.x * 96 + c);
            a0 += wv * v.x;
            a1 += wv * v.y;
        }
    }
    if (act) {
        float dn = dis[n];
        float sf = 2.f * dn * dn;
        float2 sv = *(const float2*)(xw + (size_t)n * 96 + c);
        float r0 = 0.f, r1 = 0.f;
        if (res) { float2 rv = *(const float2*)(res + (size_t)n * 96 + c); r0 = rv.x; r1 = rv.y; }
        float o0 = r0 + dn * a0 + sf * sv.x + bias[c];
        float o1 = r1 + dn * a1 + sf * sv.y + bias[c + 1];
        *(float2*)(out + (size_t)n * 96 + c) = make_float2(o0, o1);
    }
}

// ---------------- pooling ----------------
DEVINL int lbound_s(const int* a, int i64, int n, int key) {
    int lo = 0, hi = n;
    while (lo < hi) { int m = (lo + hi) >> 1; if (ld_idx(a, i64, m) < key) lo = m + 1; else hi = m; }
    return lo;
}

__global__ __launch_bounds__(128) void k_pool(const float* __restrict__ h, const int* __restrict__ batch,
                                              const int* __restrict__ flags, float* __restrict__ part) {
    int i64 = flags[1];
    int g = blockIdx.x / S, sch = blockIdx.x % S;
    int lo = lbound_s(batch, i64, N, g), hi = lbound_s(batch, i64, N, g + 1);
    int len = hi - lo;
    int a = lo + (int)(((long long)len * sch) / S);
    int b = lo + (int)(((long long)len * (sch + 1)) / S);
    int t = threadIdx.x;
    if (t < 96) {
        float sum = 0.f, mx = -INFINITY;
        for (int n = a; n < b; ++n) {
            float v = gelu_f(h[(size_t)n * 96 + t]);
            sum += v;
            mx = fmaxf(mx, v);
        }
        part[(size_t)blockIdx.x * 192 + t] = sum;
        part[(size_t)blockIdx.x * 192 + 96 + t] = mx;
    }
}

// ---------------- classifier head ----------------
__global__ __launch_bounds__(128) void k_cls(const float* __restrict__ part, const int* __restrict__ batch,
                                             const int* __restrict__ flags,
                                             const float* __restrict__ wf, void* __restrict__ outp) {
    __shared__ float p[192];
    __shared__ float q[96];
    int i64 = flags[1];
    int g = blockIdx.x, t = threadIdx.x;
    int lo = lbound_s(batch, i64, N, g), hi = lbound_s(batch, i64, N, g + 1);
    float inv = (hi > lo) ? 1.f / (float)(hi - lo) : 0.f;
    if (t < 96) {
        float sum = 0.f, mx = -INFINITY;
        for (int s = 0; s < S; ++s) {
            sum += part[(size_t)(g * S + s) * 192 + t];
            mx = fmaxf(mx, part[(size_t)(g * S + s) * 192 + 96 + t]);
        }
        p[t] = sum * inv;
        p[96 + t] = mx;
    }
    __syncthreads();
    if (t < 96) {
        float acc = wf[OFF_BC1 + t];
        const float* Wc1 = wf + OFF_WC1;
        for (int j = 0; j < 192; ++j)
            acc += p[j] * Wc1[j * 96 + t];
        q[t] = gelu_f(acc);
    }
    __syncthreads();
    if (t < 16) {
        float acc = wf[OFF_BC2 + t];
        const float* Wc2 = wf + OFF_WC2;
        for (int j = 0; j < 96; ++j)
            acc += q[j] * Wc2[j * 16 + t];
        if (flags[2]) ((float*)outp)[g * 16 + t] = acc;
        else          ((__hip_bfloat16*)outp)[g * 16 + t] = __float2bfloat16(acc);
    }
}

extern "C" void kernel_launch(void* const* d_in, const int* in_sizes, int n_in,
                              void* d_out, int out_size, void* d_ws, size_t ws_size,
                              hipStream_t stream) {
    const void* x    = d_in[0];
    const int* eidx  = (const int*)d_in[1];
    const int* batch = (const int*)d_in[2];
    (void)in_sizes; (void)n_in; (void)out_size; (void)ws_size;

    char* w = (char*)d_ws;
    size_t off = 0;
    auto take = [&](size_t bytes) { size_t o = off; off += (bytes + 511) & ~(size_t)511; return o; };
    float* dis  = (float*)(w + take((size_t)N * 4));
    int*   deg  = (int*)  (w + take((size_t)N * 4));
    int*   rp   = (int*)  (w + take((size_t)(N + 1) * 4));
    int*   cur  = (int*)  (w + take((size_t)N * 4));
    int*   bsum = (int*)  (w + take(256 * 4));
    int*   flags= (int*)  (w + take(64 * 4));
    float* wf   = (float*)(w + take((size_t)WF_TOT * 4));
    int2*  csr  = (int2*) (w + take((size_t)E * 8));
    float* bufA = (float*)(w + take((size_t)N * 96 * 4));
    float* bufH = (float*)(w + take((size_t)N * 96 * 4));
    float* part = (float*)(w + take((size_t)G * S * 192 * 4));

    hipMemsetAsync(deg, 0, (size_t)N * 4, stream);
    k_detect<<<1, 64, 0, stream>>>(eidx, batch, (const unsigned short*)x, flags);
    k_convert<<<(WF_TOT + 255) / 256, 256, 0, stream>>>(d_in[3], d_in[5], d_in[7],
                                                        d_in[9], d_in[11],
                                                        d_in[4], d_in[6], d_in[8],
                                                        d_in[10], d_in[12], flags, wf);
    k_count_deg<<<(E + 255) / 256, 256, 0, stream>>>(eidx, flags, deg);
    k_dis<<<(N + 255) / 256, 256, 0, stream>>>(deg, dis);
    int nb = (N + 1023) / 1024;
    k_scan1<<<nb, 1024, 0, stream>>>(deg, rp, bsum);
    k_scan2<<<1, 64, 0, stream>>>(bsum, nb);
    k_scan3<<<nb, 1024, 0, stream>>>(rp, bsum, cur);
    k_scatter<<<(E + 255) / 256, 256, 0, stream>>>(eidx, flags, dis, cur, csr);

    int gemm_grid = (N + 63) / 64;
    int aggr_grid = (N + 3) / 4;

    k_gemm<F_IN, 64, true, false><<<gemm_grid, 256, 0, stream>>>(x, wf + OFF_W0, flags, bufA);
    k_aggr<<<aggr_grid, 256, 0, stream>>>(bufA, nullptr, csr, rp, dis, wf + OFF_B0, bufH);
    k_gemm<H, 48, false, true><<<gemm_grid, 256, 0, stream>>>(bufH, wf + OFF_W1, flags, bufA);
    k_aggr<<<aggr_grid, 256, 0, stream>>>(bufA, bufH, csr, rp, dis, wf + OFF_B1, bufH);
    k_gemm<H, 48, false, true><<<gemm_grid, 256, 0, stream>>>(bufH, wf + OFF_W2, flags, bufA);
    k_aggr<<<aggr_grid, 256, 0, stream>>>(bufA, bufH, csr, rp, dis, wf + OFF_B2, bufH);

    k_pool<<<G * S, 128, 0, stream>>>(bufH, batch, flags, part);
    k_cls<<<G, 128, 0, stream>>>(part, batch, flags, wf, d_out);
}

// Round 4
// 466.782 us; speedup vs baseline: 1.2818x; 1.2818x over previous
//
#include <hip/hip_runtime.h>
#include <hip/hip_bf16.h>

#define DEVINL __device__ __forceinline__

constexpr int N = 50000;
constexpr int E = 800000;
constexpr int F_IN = 128;
constexpr int H = 96;
constexpr int C = 16;
constexpr int G = 128;
constexpr int S = 8;   // pooling chunks per graph

// fp32 weight table layout in ws
constexpr int OFF_W0  = 0;                    // [128][96]
constexpr int OFF_W1  = OFF_W0 + F_IN * H;    // [96][96]
constexpr int OFF_W2  = OFF_W1 + H * H;
constexpr int OFF_WC1 = OFF_W2 + H * H;       // [192][96]
constexpr int OFF_WC2 = OFF_WC1 + 2 * H * H;  // [96][16]
constexpr int OFF_B0  = OFF_WC2 + H * C;
constexpr int OFF_B1  = OFF_B0 + H;
constexpr int OFF_B2  = OFF_B1 + H;
constexpr int OFF_BC1 = OFF_B2 + H;
constexpr int OFF_BC2 = OFF_BC1 + H;
constexpr int WF_TOT  = OFF_BC2 + C;          // 51088 floats

DEVINL float gelu_f(float x) {
    return 0.5f * x * (1.0f + erff(x * 0.70710678118654752440f));
}

// ---------------- dtype detection ----------------
__global__ void k_detect(const int* __restrict__ eidx, const int* __restrict__ batch,
                         const unsigned short* __restrict__ xu, int* __restrict__ flags) {
    if (threadIdx.x == 0 && blockIdx.x == 0) {
        int z = 0;
        for (int i = 1; i < 16; i += 2) z |= eidx[i];
        flags[0] = (z == 0) ? 1 : 0;
        z = 0;
        for (int i = 20001; i < 20032; i += 2) z |= batch[i];
        flags[1] = (z == 0) ? 1 : 0;
        int bad = 0;
        for (int i = 0; i < 128; i += 2) {
            int ex = (xu[i] >> 7) & 0xFF;
            if (ex >= 132) bad = 1;
        }
        flags[2] = bad;   // 1 => fp32 storage
    }
}

DEVINL int ld_src(const int* e, int i64, int i) { return i64 ? e[2 * i] : e[i]; }
DEVINL int ld_dst(const int* e, int i64, int i) { return i64 ? e[2 * (E + i)] : e[E + i]; }
DEVINL int ld_idx(const int* a, int i64, int i) { return i64 ? a[2 * i] : a[i]; }

// ---------------- weight conversion to fp32 table ----------------
__global__ void k_convert(const void* W0, const void* W1, const void* W2,
                          const void* Wc1, const void* Wc2,
                          const void* b0, const void* b1, const void* b2,
                          const void* bc1, const void* bc2,
                          const int* __restrict__ flags, float* __restrict__ wf) {
    int i = blockIdx.x * 256 + threadIdx.x;
    if (i >= WF_TOT) return;
    int f32 = flags[2];
    const void* src; int j;
    if      (i < OFF_W1)  { src = W0;  j = i - OFF_W0; }
    else if (i < OFF_W2)  { src = W1;  j = i - OFF_W1; }
    else if (i < OFF_WC1) { src = W2;  j = i - OFF_W2; }
    else if (i < OFF_WC2) { src = Wc1; j = i - OFF_WC1; }
    else if (i < OFF_B0)  { src = Wc2; j = i - OFF_WC2; }
    else if (i < OFF_B1)  { src = b0;  j = i - OFF_B0; }
    else if (i < OFF_B2)  { src = b1;  j = i - OFF_B1; }
    else if (i < OFF_BC1) { src = b2;  j = i - OFF_B2; }
    else if (i < OFF_BC2) { src = bc1; j = i - OFF_BC1; }
    else                  { src = bc2; j = i - OFF_BC2; }
    wf[i] = f32 ? ((const float*)src)[j]
                : __bfloat162float(((const __hip_bfloat16*)src)[j]);
}

// ---------------- degree ----------------
__global__ void k_count_deg(const int* __restrict__ eidx, const int* __restrict__ flags,
                            int* __restrict__ cnt) {
    int e = blockIdx.x * 256 + threadIdx.x;
    int i64 = flags[0];
    if (e < E) atomicAdd(&cnt[ld_dst(eidx, i64, e)], 1);
}

// ---------------- exclusive scan over N counts (+ dis folded in) ----------------
__global__ __launch_bounds__(1024) void k_scan1(const int* __restrict__ cnt,
                                                int* __restrict__ rp, int* __restrict__ bsum,
                                                float* __restrict__ dis) {
    __shared__ int sd[1024];
    int t = threadIdx.x;
    int i = blockIdx.x * 1024 + t;
    int v = (i < N) ? cnt[i] : 0;
    if (i < N) dis[i] = rsqrtf((float)v + 2.0f);
    sd[t] = v; __syncthreads();
    for (int off = 1; off < 1024; off <<= 1) {
        int u = (t >= off) ? sd[t - off] : 0;
        __syncthreads();
        sd[t] += u;
        __syncthreads();
    }
    if (i < N) rp[i] = sd[t] - v;
    if (t == 1023) bsum[blockIdx.x] = sd[1023];
}

__global__ void k_scan2(int* __restrict__ bsum, int nb) {
    __shared__ int sd[64];
    int t = threadIdx.x;
    int v = (t < nb) ? bsum[t] : 0;
    sd[t] = v; __syncthreads();
    for (int off = 1; off < 64; off <<= 1) {
        int u = (t >= off) ? sd[t - off] : 0;
        __syncthreads();
        sd[t] += u;
        __syncthreads();
    }
    if (t < nb) bsum[t] = sd[t] - v;
}

__global__ __launch_bounds__(1024) void k_scan3(int* __restrict__ rp, const int* __restrict__ bsum,
                                                int* __restrict__ cur) {
    int t = threadIdx.x;
    int i = blockIdx.x * 1024 + t;
    if (i < N) { int v = rp[i] + bsum[blockIdx.x]; rp[i] = v; cur[i] = v; }
    if (i == 0) rp[N] = E;
}

// ---------------- CSR scatter (by dst), store (src, dis[src]) ----------------
__global__ void k_scatter(const int* __restrict__ eidx, const int* __restrict__ flags,
                          const float* __restrict__ dis, int* __restrict__ cur,
                          int2* __restrict__ csr) {
    int e = blockIdx.x * 256 + threadIdx.x;
    int i64 = flags[0];
    if (e < E) {
        int s = ld_src(eidx, i64, e), d = ld_dst(eidx, i64, e);
        int p = atomicAdd(&cur[d], 1);
        csr[p] = make_int2(s, __float_as_int(dis[s]));
    }
}

// ---------------- node GEMM: out[N,96] = op(in[N,K]) @ Wf[K,96] ----------------
// 64 rows/block, 128 threads, 8x6 outputs per thread. 48 FMA : 5 LDS ops.
template<int K, int KC, bool RAW_IN, bool GELU_IN>
__global__ __launch_bounds__(128) void k_gemm(const void* __restrict__ inp,
                                              const float* __restrict__ Wf,
                                              const int* __restrict__ flags,
                                              float* __restrict__ out) {
    constexpr int R = 64;
    constexpr int NC = K / KC;
    __shared__ __align__(16) float xs[KC][R + 4];
    __shared__ __align__(16) float wsh[KC * 96];
    const int t = threadIdx.x;          // 0..127
    const int r0 = blockIdx.x * R;
    const int xf32 = RAW_IN ? flags[2] : 1;
    const int ty = t >> 4;              // 0..7 -> rows ty*8..+7
    const int tx = t & 15;              // cols tx*6..+5

    float acc[8][6];
#pragma unroll
    for (int i = 0; i < 8; ++i)
#pragma unroll
        for (int j = 0; j < 6; ++j) acc[i][j] = 0.f;

    for (int c = 0; c < NC; ++c) {
        if (c) __syncthreads();
        // stage W chunk (float4)
        for (int idx = t * 4; idx < KC * 96; idx += 128 * 4)
            *(float4*)&wsh[idx] = *(const float4*)&Wf[c * KC * 96 + idx];
        // stage x chunk transposed
        if (RAW_IN && !xf32) {
            for (int idx = t; idx < R * KC; idx += 128) {
                int r = idx / KC, kk = idx - r * KC;
                int row = r0 + r, k = c * KC + kk;
                float v = 0.f;
                if (row < N) v = __bfloat162float(((const __hip_bfloat16*)inp)[(size_t)row * K + k]);
                xs[kk][r] = v;
            }
        } else {
            for (int idx = t; idx < R * (KC / 4); idx += 128) {
                int r = idx / (KC / 4), k4 = (idx - r * (KC / 4)) * 4;
                int row = r0 + r, k = c * KC + k4;
                float4 v = make_float4(0.f, 0.f, 0.f, 0.f);
                if (row < N) v = *(const float4*)((const float*)inp + (size_t)row * K + k);
                if (GELU_IN) { v.x = gelu_f(v.x); v.y = gelu_f(v.y); v.z = gelu_f(v.z); v.w = gelu_f(v.w); }
                xs[k4 + 0][r] = v.x; xs[k4 + 1][r] = v.y; xs[k4 + 2][r] = v.z; xs[k4 + 3][r] = v.w;
            }
        }
        __syncthreads();

#pragma unroll 2
        for (int kk = 0; kk < KC; ++kk) {
            float4 a0 = *(const float4*)&xs[kk][ty * 8];
            float4 a1 = *(const float4*)&xs[kk][ty * 8 + 4];
            float2 b0 = *(const float2*)&wsh[kk * 96 + tx * 6];
            float2 b1 = *(const float2*)&wsh[kk * 96 + tx * 6 + 2];
            float2 b2 = *(const float2*)&wsh[kk * 96 + tx * 6 + 4];
            float a[8] = {a0.x, a0.y, a0.z, a0.w, a1.x, a1.y, a1.z, a1.w};
            float b[6] = {b0.x, b0.y, b1.x, b1.y, b2.x, b2.y};
#pragma unroll
            for (int i = 0; i < 8; ++i)
#pragma unroll
                for (int j = 0; j < 6; ++j)
                    acc[i][j] = fmaf(a[i], b[j], acc[i][j]);
        }
    }

#pragma unroll
    for (int i = 0; i < 8; ++i) {
        int row = r0 + ty * 8 + i;
        if (row < N) {
            float* o = out + (size_t)row * 96 + tx * 6;
            *(float2*)(o + 0) = make_float2(acc[i][0], acc[i][1]);
            *(float2*)(o + 2) = make_float2(acc[i][2], acc[i][3]);
            *(float2*)(o + 4) = make_float2(acc[i][4], acc[i][5]);
        }
    }
}

// ---------------- aggregation: out = res + dis[n]*sum + 2*dis^2*xw[n] + b ----------------
// one wave per node; lanes 0-47 = 2 edge-slots x 24 lanes, float4 per lane.
__global__ __launch_bounds__(256) void k_aggr(const float* __restrict__ xw, const float* res,
                                              const int2* __restrict__ csr, const int* __restrict__ rp,
                                              const float* __restrict__ dis,
                                              const float* __restrict__ bias, float* __restrict__ out) {
    int wid = threadIdx.x >> 6, lane = threadIdx.x & 63;
    int n = blockIdx.x * 4 + wid;
    if (n >= N) return;
    int e0 = rp[n], e1 = rp[n + 1];
    int slot = lane / 24;            // 0,1 active; 2 idle
    int cl = (lane % 24) * 4;
    float4 acc = make_float4(0.f, 0.f, 0.f, 0.f);
    int eb = (slot < 2) ? (e0 + slot) : e1;
#pragma unroll 2
    for (; eb < e1; eb += 2) {
        int2 q = csr[eb];            // 24-lane broadcast
        float w = __int_as_float(q.y);
        const float4 v = *(const float4*)(xw + (size_t)q.x * 96 + cl);
        acc.x = fmaf(w, v.x, acc.x); acc.y = fmaf(w, v.y, acc.y);
        acc.z = fmaf(w, v.z, acc.z); acc.w = fmaf(w, v.w, acc.w);
    }
    // combine slot 1 (lanes 24-47) into slot 0 (lanes 0-23)
    int p = lane + 24;
    float ox = __shfl(acc.x, p), oy = __shfl(acc.y, p);
    float oz = __shfl(acc.z, p), ow = __shfl(acc.w, p);
    if (lane < 24) {
        acc.x += ox; acc.y += oy; acc.z += oz; acc.w += ow;
        float dn = dis[n], sf = 2.f * dn * dn;
        float4 sv = *(const float4*)(xw + (size_t)n * 96 + cl);
        float4 bv = *(const float4*)(bias + cl);
        float4 rv = make_float4(0.f, 0.f, 0.f, 0.f);
        if (res) rv = *(const float4*)(res + (size_t)n * 96 + cl);
        float4 o;
        o.x = rv.x + dn * acc.x + sf * sv.x + bv.x;
        o.y = rv.y + dn * acc.y + sf * sv.y + bv.y;
        o.z = rv.z + dn * acc.z + sf * sv.z + bv.z;
        o.w = rv.w + dn * acc.w + sf * sv.w + bv.w;
        *(float4*)(out + (size_t)n * 96 + cl) = o;
    }
}

// ---------------- pooling ----------------
DEVINL int lbound_s(const int* a, int i64, int n, int key) {
    int lo = 0, hi = n;
    while (lo < hi) { int m = (lo + hi) >> 1; if (ld_idx(a, i64, m) < key) lo = m + 1; else hi = m; }
    return lo;
}

__global__ __launch_bounds__(128) void k_pool(const float* __restrict__ h, const int* __restrict__ batch,
                                              const int* __restrict__ flags, float* __restrict__ part) {
    int i64 = flags[1];
    int g = blockIdx.x / S, sch = blockIdx.x % S;
    int lo = lbound_s(batch, i64, N, g), hi = lbound_s(batch, i64, N, g + 1);
    int len = hi - lo;
    int a = lo + (int)(((long long)len * sch) / S);
    int b = lo + (int)(((long long)len * (sch + 1)) / S);
    int t = threadIdx.x;
    if (t < 96) {
        float sum = 0.f, mx = -INFINITY;
        for (int n = a; n < b; ++n) {
            float v = gelu_f(h[(size_t)n * 96 + t]);
            sum += v;
            mx = fmaxf(mx, v);
        }
        part[(size_t)blockIdx.x * 192 + t] = sum;
        part[(size_t)blockIdx.x * 192 + 96 + t] = mx;
    }
}

// ---------------- classifier head ----------------
__global__ __launch_bounds__(128) void k_cls(const float* __restrict__ part, const int* __restrict__ batch,
                                             const int* __restrict__ flags,
                                             const float* __restrict__ wf, void* __restrict__ outp) {
    __shared__ float p[192];
    __shared__ float q[96];
    int i64 = flags[1];
    int g = blockIdx.x, t = threadIdx.x;
    int lo = lbound_s(batch, i64, N, g), hi = lbound_s(batch, i64, N, g + 1);
    float inv = (hi > lo) ? 1.f / (float)(hi - lo) : 0.f;
    if (t < 96) {
        float sum = 0.f, mx = -INFINITY;
        for (int s = 0; s < S; ++s) {
            sum += part[(size_t)(g * S + s) * 192 + t];
            mx = fmaxf(mx, part[(size_t)(g * S + s) * 192 + 96 + t]);
        }
        p[t] = sum * inv;
        p[96 + t] = mx;
    }
    __syncthreads();
    if (t < 96) {
        float acc = wf[OFF_BC1 + t];
        const float* Wc1 = wf + OFF_WC1;
        for (int j = 0; j < 192; ++j)
            acc += p[j] * Wc1[j * 96 + t];
        q[t] = gelu_f(acc);
    }
    __syncthreads();
    if (t < 16) {
        float acc = wf[OFF_BC2 + t];
        const float* Wc2 = wf + OFF_WC2;
        for (int j = 0; j < 96; ++j)
            acc += q[j] * Wc2[j * 16 + t];
        if (flags[2]) ((float*)outp)[g * 16 + t] = acc;
        else          ((__hip_bfloat16*)outp)[g * 16 + t] = __float2bfloat16(acc);
    }
}

extern "C" void kernel_launch(void* const* d_in, const int* in_sizes, int n_in,
                              void* d_out, int out_size, void* d_ws, size_t ws_size,
                              hipStream_t stream) {
    const void* x    = d_in[0];
    const int* eidx  = (const int*)d_in[1];
    const int* batch = (const int*)d_in[2];
    (void)in_sizes; (void)n_in; (void)out_size; (void)ws_size;

    char* w = (char*)d_ws;
    size_t off = 0;
    auto take = [&](size_t bytes) { size_t o = off; off += (bytes + 511) & ~(size_t)511; return o; };
    float* dis  = (float*)(w + take((size_t)N * 4));
    int*   deg  = (int*)  (w + take((size_t)N * 4));
    int*   rp   = (int*)  (w + take((size_t)(N + 1) * 4));
    int*   cur  = (int*)  (w + take((size_t)N * 4));
    int*   bsum = (int*)  (w + take(256 * 4));
    int*   flags= (int*)  (w + take(64 * 4));
    float* wf   = (float*)(w + take((size_t)WF_TOT * 4));
    int2*  csr  = (int2*) (w + take((size_t)E * 8));
    float* bufA = (float*)(w + take((size_t)N * 96 * 4));
    float* bufH = (float*)(w + take((size_t)N * 96 * 4));
    float* part = (float*)(w + take((size_t)G * S * 192 * 4));

    hipMemsetAsync(deg, 0, (size_t)N * 4, stream);
    k_detect<<<1, 64, 0, stream>>>(eidx, batch, (const unsigned short*)x, flags);
    k_convert<<<(WF_TOT + 255) / 256, 256, 0, stream>>>(d_in[3], d_in[5], d_in[7],
                                                        d_in[9], d_in[11],
                                                        d_in[4], d_in[6], d_in[8],
                                                        d_in[10], d_in[12], flags, wf);
    k_count_deg<<<(E + 255) / 256, 256, 0, stream>>>(eidx, flags, deg);
    int nb = (N + 1023) / 1024;
    k_scan1<<<nb, 1024, 0, stream>>>(deg, rp, bsum, dis);
    k_scan2<<<1, 64, 0, stream>>>(bsum, nb);
    k_scan3<<<nb, 1024, 0, stream>>>(rp, bsum, cur);
    k_scatter<<<(E + 255) / 256, 256, 0, stream>>>(eidx, flags, dis, cur, csr);

    int gemm_grid = (N + 63) / 64;
    int aggr_grid = (N + 3) / 4;

    k_gemm<F_IN, 64, true, false><<<gemm_grid, 128, 0, stream>>>(x, wf + OFF_W0, flags, bufA);
    k_aggr<<<aggr_grid, 256, 0, stream>>>(bufA, nullptr, csr, rp, dis, wf + OFF_B0, bufH);
    k_gemm<H, 48, false, true><<<gemm_grid, 128, 0, stream>>>(bufH, wf + OFF_W1, flags, bufA);
    k_aggr<<<aggr_grid, 256, 0, stream>>>(bufA, bufH, csr, rp, dis, wf + OFF_B1, bufH);
    k_gemm<H, 48, false, true><<<gemm_grid, 128, 0, stream>>>(bufH, wf + OFF_W2, flags, bufA);
    k_aggr<<<aggr_grid, 256, 0, stream>>>(bufA, bufH, csr, rp, dis, wf + OFF_B2, bufH);

    k_pool<<<G * S, 128, 0, stream>>>(bufH, batch, flags, part);
    k_cls<<<G, 128, 0, stream>>>(part, batch, flags, wf, d_out);
}